// Round 3
// baseline (10187.879 us; speedup 1.0000x reference)
//
#include <hip/hip_runtime.h>

// Decoder_8014408974552 R3: R2 structure (32x32x16 bf16 MFMA, block-cooperative
// global_load_lds weight streaming, 50 double-buffered phases/step) with the
// register-spill fix: hnew[] registers eliminated. Each wave keeps a private
// persistent LDS h-buffer (hn, 32x392 u16); blend writes old-h frags there,
// blends in place, and hold[] regs are reloaded once per step (24 ds_read_b128).
// Peak VGPR demand ~220 (was ~290 -> scratch spills, 187 MB/launch).

#define TT  30
#define NPH 50
#define PHU 12288   // u16 per phase (24576 B)
#define HS  392     // hn row stride in u16 (784 B, 16B-aligned)

typedef unsigned short u16;
typedef __bf16 bf16x8 __attribute__((ext_vector_type(8)));
typedef u16    u16x8  __attribute__((ext_vector_type(8)));
typedef float  f32x16 __attribute__((ext_vector_type(16)));

__device__ __forceinline__ u16 f2b(float f){           // fp32 -> bf16 RNE
  unsigned u = __float_as_uint(f);
  u += 0x7FFFu + ((u >> 16) & 1u);
  return (u16)(u >> 16);
}
__device__ __forceinline__ float b2f(u16 h){ return __uint_as_float(((unsigned)h) << 16); }

__device__ __forceinline__ f32x16 mfma32(u16x8 a, u16x8 b, f32x16 c){
  return __builtin_amdgcn_mfma_f32_32x32x16_bf16(
      __builtin_bit_cast(bf16x8, a), __builtin_bit_cast(bf16x8, b), c, 0, 0, 0);
}
__device__ __forceinline__ void lds_fence(){ asm volatile("s_waitcnt lgkmcnt(0)" ::: "memory"); }
__device__ __forceinline__ void vm_fence(){ asm volatile("s_waitcnt vmcnt(0)" ::: "memory"); }
__device__ __forceinline__ float sigf(float x){ return __builtin_amdgcn_rcpf(1.f + __expf(-x)); }
__device__ __forceinline__ float tanh_(float x){ return 2.f*__builtin_amdgcn_rcpf(1.f + __expf(-2.f*x)) - 1.f; }

__device__ __forceinline__ void stage16(const u16* g, u16* l){
  __builtin_amdgcn_global_load_lds(
      (const __attribute__((address_space(1))) unsigned int*)g,
      (__attribute__((address_space(3))) unsigned int*)l, 16, 0, 0);
}

// ---------------------------------------------------------------- prep ----
// Stream layout identical to R2 (50 phases x 24 frags x 1024 B per step):
//   c*4+0 : gi  [gi_r kf0..7][gi_z kf0..7][gi_n kf0..7]   (K=128)
//   c*4+1 : gh_r kf0..23   c*4+2 : gh_z   c*4+3 : gh_n     (K=384)
//   48,49 : Wd1 col-tile 0,1  kf0..23
// frag: u16 idx (lane&31 + 32*(lane>>5))*8 + j -> B[k][n], n=c*32+(lane&31),
// k = kf*16 + (lane>>5)*8 + j
__global__ void prep_kernel(const float* __restrict__ Wih, const float* __restrict__ Whh,
                            const float* __restrict__ Wd1, const float* __restrict__ Wd2,
                            const float* __restrict__ bih, const float* __restrict__ bhh,
                            const float* __restrict__ Ws,  const float* __restrict__ bs,
                            const float* __restrict__ Wp,  const float* __restrict__ bp,
                            u16* __restrict__ stream, u16* __restrict__ wd2p,
                            u16* __restrict__ wxp, float* __restrict__ gb)
{
  int i = blockIdx.x*blockDim.x + threadIdx.x;
  if (i < 442368){  // W_hh [1152][384]
    int row = i/384, k = i - row*384;
    int g = row/384, unit = row - g*384, c = unit>>5, lc = unit&31;
    int kf = k>>4, hl = (k>>3)&1, j = k&7;
    int phase = c*4 + 1 + g;
    stream[(size_t)phase*PHU + kf*512 + (lc+32*hl)*8 + j] = f2b(Whh[i]);
  }
  if (i < 147456){  // W_ih [1152][128]
    int row = i>>7, k = i&127;
    int g = row/384, unit = row - g*384, c = unit>>5, lc = unit&31;
    int kf = k>>4, hl = (k>>3)&1, j = k&7;
    int phase = c*4;
    stream[(size_t)phase*PHU + (g*8+kf)*512 + (lc+32*hl)*8 + j] = f2b(Wih[i]);
  }
  if (i < 24576){   // Wd1 [64][384]
    int row = i/384, k = i - row*384;
    int ct = row>>5, lc = row&31;
    int kf = k>>4, hl = (k>>3)&1, j = k&7;
    int phase = 48 + ct;
    stream[(size_t)phase*PHU + kf*512 + (lc+32*hl)*8 + j] = f2b(Wd1[i]);
  }
  if (i < 2048){    // Wd2 padded B-frags [4 kf][512] (n>=3 -> 0)
    int kf = i>>9, r = i&511;
    int n = (r>>3)&31, hl = r>>8, j = r&7;
    int k = kf*16 + hl*8 + j;
    wd2p[i] = f2b((n<3) ? Wd2[n*64 + k] : 0.f);
  }
  if (i < 2048){    // x-MLP B-frags [4 tiles][512]: K=16 (k=0..7 feat, 8..15 zero)
    int tl = i>>9, r = i&511;
    int n = (r>>3)&31, hl = r>>8, j = r&7;
    int k = hl*8 + j, u = tl*32 + n;
    float v = 0.f;
    if      (k <= 2) v = Ws[u*3 + k];
    else if (k == 3) v = bs[u];
    else if (k <= 6) v = Wp[u*3 + (k-4)];
    else if (k == 7) v = bp[u];
    wxp[i] = f2b(v);
  }
  if (i < 384){     // fused gate biases per hidden unit: {r, z, n_i, n_h}
    gb[i*4+0] = bih[i]       + bhh[i];
    gb[i*4+1] = bih[384+i]   + bhh[384+i];
    gb[i*4+2] = bih[768+i];
    gb[i*4+3] = bhh[768+i];
  }
}

// ---------------------------------------------------------------- main ----
__global__ __launch_bounds__(256, 1)
void gru_main(const float* __restrict__ ih, const float* __restrict__ plan,
              const float* __restrict__ gate, const float* __restrict__ istate,
              const u16* __restrict__ stream, const u16* __restrict__ wd2p,
              const u16* __restrict__ wxp, const float* __restrict__ gb,
              const float* __restrict__ bd1, const float* __restrict__ bd2,
              float* __restrict__ out)
{
  __shared__ __attribute__((aligned(16))) u16 wb[2][PHU];   // 49152 B
  __shared__ __attribute__((aligned(16))) u16 hn[4][32*HS]; // 100352 B (wave-private h)
  __shared__ float sst[4][32][4];                           //   2048 B

  const int tid  = threadIdx.x;
  const int wave = tid >> 6, lane = tid & 63;
  const int m    = lane & 31, hl = lane >> 5;
  const int R0   = blockIdx.x*128 + wave*32;   // wave's 32 batch rows
  u16* hw = hn[wave];

  const float gt    = gate[R0 + m];
  const float bd1v0 = bd1[m], bd1v1 = bd1[32+m];
  const float bd2v  = (m<3) ? bd2[m] : 0.f;

  if (lane < 32){
    const float* sp = istate + (size_t)(R0+lane)*3;
    sst[wave][lane][0]=sp[0]; sst[wave][lane][1]=sp[1];
    sst[wave][lane][2]=sp[2]; sst[wave][lane][3]=0.f;
  }

  // initial hidden -> A-frags: hold[kf] = h[m][kf*16 + hl*8 + j]
  u16x8 hold[24];
#pragma unroll
  for (int kf=0; kf<24; ++kf){
    const float* p = ih + (size_t)(R0+m)*384 + kf*16 + hl*8;
    float4 a = *(const float4*)p;
    float4 b = *(const float4*)(p+4);
    u16x8 v;
    v[0]=f2b(a.x); v[1]=f2b(a.y); v[2]=f2b(a.z); v[3]=f2b(a.w);
    v[4]=f2b(b.x); v[5]=f2b(b.y); v[6]=f2b(b.z); v[7]=f2b(b.w);
    hold[kf]=v;
  }

  const u16* srcb = stream + wave*3072 + lane*8;  // this wave's quarter + lane slot
  auto stage = [&](int ph, int bsel){
    const u16* s = srcb + (size_t)ph*PHU;
    u16* d = &wb[bsel][wave*3072];
#pragma unroll
    for (int ii=0; ii<6; ++ii) stage16(s + ii*512, d + ii*512);
  };

  stage(0, 0);
  vm_fence(); __syncthreads();
  int buf = 0, gp = 0;

#pragma unroll 1
  for (int t=0; t<TT; ++t){
    // ---- x = (state@Ws^T+bs) + gate*(plan@Wp^T+bp) via one padded-K MFMA per tile
    u16x8 a8;
    {
      float4 sv = *(const float4*)&sst[wave][m][0];
      const float* pp = plan + (size_t)(R0+m)*(TT*3) + t*3;
      float f0=sv.x, f1=sv.y, f2=sv.z, f3=1.f;
      float f4=gt*pp[0], f5=gt*pp[1], f6=gt*pp[2], f7=gt;
      if (hl){ a8[0]=0;a8[1]=0;a8[2]=0;a8[3]=0;a8[4]=0;a8[5]=0;a8[6]=0;a8[7]=0; }
      else { a8[0]=f2b(f0);a8[1]=f2b(f1);a8[2]=f2b(f2);a8[3]=f2b(f3);
             a8[4]=f2b(f4);a8[5]=f2b(f5);a8[6]=f2b(f6);a8[7]=f2b(f7); }
    }
    u16x8 xf[8];
#pragma unroll
    for (int tl=0; tl<4; ++tl){
      f32x16 ax;
#pragma unroll
      for (int r=0;r<16;++r) ax[r]=0.f;
      ax = mfma32(a8, *(const u16x8*)(wxp + tl*512 + lane*8), ax);
      // C-layout -> hn scratch -> A-frags (hn slice safe: rewritten before read)
#pragma unroll
      for (int r=0;r<16;++r){
        int row = (r&3) + ((r>>2)<<3) + 4*hl;
        hw[row*HS + m] = f2b(ax[r]);
      }
      lds_fence();
      xf[2*tl]   = *(const u16x8*)&hw[m*HS + hl*8];
      xf[2*tl+1] = *(const u16x8*)&hw[m*HS + 16 + hl*8];
      lds_fence();
    }

#pragma unroll 1
    for (int c=0; c<12; ++c){
      f32x16 aR, aZ, aNI, aNH;
      {
        const float4 b4 = *(const float4*)(gb + (size_t)(c*32+m)*4);
#pragma unroll
        for (int r=0;r<16;++r){ aR[r]=b4.x; aZ[r]=b4.y; aNI[r]=b4.z; aNH[r]=b4.w; }
      }
      { // phase c*4: gi (r,z,n from x)
        int np = gp+1; stage(np, buf^1);
        const u16* W = wb[buf];
#pragma unroll
        for (int kf=0; kf<8; ++kf){
          u16x8 bR = *(const u16x8*)(W + (kf    )*512 + lane*8);
          u16x8 bZ = *(const u16x8*)(W + (8+kf  )*512 + lane*8);
          u16x8 bN = *(const u16x8*)(W + (16+kf )*512 + lane*8);
          aR  = mfma32(xf[kf], bR, aR);
          aZ  = mfma32(xf[kf], bZ, aZ);
          aNI = mfma32(xf[kf], bN, aNI);
        }
        vm_fence(); __syncthreads(); buf^=1; gp=np;
      }
      { // phase c*4+1: gh_r
        int np = gp+1; stage(np, buf^1);
        const u16* W = wb[buf];
#pragma unroll
        for (int kf=0; kf<24; ++kf)
          aR = mfma32(hold[kf], *(const u16x8*)(W + kf*512 + lane*8), aR);
        vm_fence(); __syncthreads(); buf^=1; gp=np;
      }
      { // phase c*4+2: gh_z
        int np = gp+1; stage(np, buf^1);
        const u16* W = wb[buf];
#pragma unroll
        for (int kf=0; kf<24; ++kf)
          aZ = mfma32(hold[kf], *(const u16x8*)(W + kf*512 + lane*8), aZ);
        vm_fence(); __syncthreads(); buf^=1; gp=np;
      }
      { // phase c*4+3: gh_n + GRU elementwise, blended in place in hn slice
        int np = gp+1; stage(np, buf^1);
        const u16* W = wb[buf];
#pragma unroll
        for (int kf=0; kf<24; ++kf)
          aNH = mfma32(hold[kf], *(const u16x8*)(W + kf*512 + lane*8), aNH);
        // old h chunk (A-layout regs) -> hn chunk slice
        *(u16x8*)&hw[m*HS + c*32 + hl*8]      = hold[2*c];
        *(u16x8*)&hw[m*HS + c*32 + 16 + hl*8] = hold[2*c+1];
        lds_fence();
#pragma unroll
        for (int r=0;r<16;++r){
          int row = (r&3) + ((r>>2)<<3) + 4*hl;
          float rr = sigf(aR[r]);
          float zz = sigf(aZ[r]);
          float nn = tanh_(aNI[r] + rr*aNH[r]);
          int off = row*HS + c*32 + m;
          float ho = b2f(hw[off]);             // old h (same lane wrote this addr)
          hw[off] = f2b((1.f-zz)*nn + zz*ho);  // new h, in place
        }
        vm_fence(); __syncthreads(); buf^=1; gp=np;
      }
    } // chunks

    // ---- reload hold[] from hn (full new h for this wave's 32 rows)
    lds_fence();
#pragma unroll
    for (int kf=0; kf<24; ++kf)
      hold[kf] = *(const u16x8*)&hw[m*HS + kf*16 + hl*8];

    // ---- decode: d1 = elu(h@Wd1^T + bd1) [2 tiles], then d2 via padded-N MFMA
    f32x16 a0, a1;
#pragma unroll
    for (int r=0;r<16;++r){ a0[r]=bd1v0; a1[r]=bd1v1; }
    { // phase 48: Wd1 tile 0
      int np = gp+1; stage(np, buf^1);
      const u16* W = wb[buf];
#pragma unroll
      for (int kf=0; kf<24; ++kf)
        a0 = mfma32(hold[kf], *(const u16x8*)(W + kf*512 + lane*8), a0);
      vm_fence(); __syncthreads(); buf^=1; gp=np;
    }
    { // phase 49: Wd1 tile 1 (+ epilogue); next stage wraps to phase 0
      int np = (gp+1 == NPH) ? 0 : gp+1;
      stage(np, buf^1);
      const u16* W = wb[buf];
#pragma unroll
      for (int kf=0; kf<24; ++kf)
        a1 = mfma32(hold[kf], *(const u16x8*)(W + kf*512 + lane*8), a1);

      // Wd2 frags loaded here (short live range, L1-hot)
      u16x8 wd2f0 = *(const u16x8*)(wd2p + 0*512 + lane*8);
      u16x8 wd2f1 = *(const u16x8*)(wd2p + 1*512 + lane*8);
      u16x8 wd2f2 = *(const u16x8*)(wd2p + 2*512 + lane*8);
      u16x8 wd2f3 = *(const u16x8*)(wd2p + 3*512 + lane*8);

      f32x16 ao;
#pragma unroll
      for (int r=0;r<16;++r) ao[r]=0.f;
      // pass 0: d1 units 0..31 (hn free for scratch after hold reload)
#pragma unroll
      for (int r=0;r<16;++r){
        int row = (r&3) + ((r>>2)<<3) + 4*hl;
        float e = a0[r]; e = e>0.f ? e : (__expf(e)-1.f);
        hw[row*HS + m] = f2b(e);
      }
      lds_fence();
      {
        u16x8 af0 = *(const u16x8*)&hw[m*HS + hl*8];
        u16x8 af1 = *(const u16x8*)&hw[m*HS + 16 + hl*8];
        ao = mfma32(af0, wd2f0, ao);
        ao = mfma32(af1, wd2f1, ao);
      }
      lds_fence();
      // pass 1: d1 units 32..63
#pragma unroll
      for (int r=0;r<16;++r){
        int row = (r&3) + ((r>>2)<<3) + 4*hl;
        float e = a1[r]; e = e>0.f ? e : (__expf(e)-1.f);
        hw[row*HS + m] = f2b(e);
      }
      lds_fence();
      {
        u16x8 af0 = *(const u16x8*)&hw[m*HS + hl*8];
        u16x8 af1 = *(const u16x8*)&hw[m*HS + 16 + hl*8];
        ao = mfma32(af0, wd2f2, ao);
        ao = mfma32(af1, wd2f3, ao);
      }
      // out + state update (C cols 0..2 valid)
#pragma unroll
      for (int r=0;r<16;++r){
        int row = (r&3) + ((r>>2)<<3) + 4*hl;
        if (m < 3){
          float ns = sst[wave][row][m] + ao[r] + bd2v;
          out[(size_t)(R0+row)*(TT*3) + t*3 + m] = ns;
          sst[wave][row][m] = ns;
        }
      }
      vm_fence(); __syncthreads(); buf^=1; gp=np;
    }
  } // t
}

// -------------------------------------------------------------- launch ----
extern "C" void kernel_launch(void* const* d_in, const int* in_sizes, int n_in,
                              void* d_out, int out_size, void* d_ws, size_t ws_size,
                              hipStream_t stream)
{
  (void)in_sizes; (void)n_in; (void)out_size; (void)ws_size;
  const float* ih     = (const float*)d_in[0];
  const float* plan   = (const float*)d_in[1];
  const float* gatep  = (const float*)d_in[2];
  const float* istate = (const float*)d_in[3];
  const float* Wp     = (const float*)d_in[4];
  const float* bp     = (const float*)d_in[5];
  const float* Ws     = (const float*)d_in[6];
  const float* bs     = (const float*)d_in[7];
  const float* Wih    = (const float*)d_in[8];
  const float* bih    = (const float*)d_in[9];
  const float* Whh    = (const float*)d_in[10];
  const float* bhh    = (const float*)d_in[11];
  const float* Wd1    = (const float*)d_in[12];
  const float* bd1    = (const float*)d_in[13];
  const float* Wd2    = (const float*)d_in[14];
  const float* bd2    = (const float*)d_in[15];

  // workspace layout (~1.25 MB)
  u16*   wstream = (u16*)d_ws;                         // 614400 u16 = 1228800 B
  u16*   wd2p    = (u16*)((char*)d_ws + 1228800);      //   2048 u16 =    4096 B
  u16*   wxp     = (u16*)((char*)d_ws + 1232896);      //   2048 u16 =    4096 B
  float* gb      = (float*)((char*)d_ws + 1236992);    //   1536 f32 =    6144 B

  prep_kernel<<<1728, 256, 0, stream>>>(Wih, Whh, Wd1, Wd2, bih, bhh, Ws, bs, Wp, bp,
                                        wstream, wd2p, wxp, gb);
  gru_main<<<256, 256, 0, stream>>>(ih, plan, gatep, istate,
                                    wstream, wd2p, wxp, gb, bd1, bd2, (float*)d_out);
}

// Round 4
// 1729.000 us; speedup vs baseline: 5.8924x; 5.8924x over previous
//
#include <hip/hip_runtime.h>

// Decoder_8014408974552 R4: R3 structure with the scratch-demotion fix.
// ROOT CAUSE of R2/R3 slowness: runtime-indexed register arrays
// (hold[2*c] / hnew[2*c]) force the compiler to demote the whole array to
// scratch memory -> ~30 GB/launch of hidden HBM traffic (R3: FETCH 16.8 GB,
// WRITE 13.3 GB). Fix: hn (wave-private LDS h) is initialized once and
// blended in place; the only runtime-indexed register access is deleted.
// Transpose scratch uses hn's chunk-0 slice, restored from hold[0]/hold[1]
// (constant indices) after each use.

#define TT  30
#define NPH 50
#define PHU 12288   // u16 per phase (24576 B)
#define HS  392     // hn row stride in u16 (784 B, 16B-aligned, 0 conflicts)

typedef unsigned short u16;
typedef __bf16 bf16x8 __attribute__((ext_vector_type(8)));
typedef u16    u16x8  __attribute__((ext_vector_type(8)));
typedef float  f32x16 __attribute__((ext_vector_type(16)));

__device__ __forceinline__ u16 f2b(float f){           // fp32 -> bf16 RNE
  unsigned u = __float_as_uint(f);
  u += 0x7FFFu + ((u >> 16) & 1u);
  return (u16)(u >> 16);
}
__device__ __forceinline__ float b2f(u16 h){ return __uint_as_float(((unsigned)h) << 16); }

__device__ __forceinline__ f32x16 mfma32(u16x8 a, u16x8 b, f32x16 c){
  return __builtin_amdgcn_mfma_f32_32x32x16_bf16(
      __builtin_bit_cast(bf16x8, a), __builtin_bit_cast(bf16x8, b), c, 0, 0, 0);
}
__device__ __forceinline__ void lds_fence(){ asm volatile("s_waitcnt lgkmcnt(0)" ::: "memory"); }
__device__ __forceinline__ void vm_fence(){ asm volatile("s_waitcnt vmcnt(0)" ::: "memory"); }
__device__ __forceinline__ float sigf(float x){ return __builtin_amdgcn_rcpf(1.f + __expf(-x)); }
__device__ __forceinline__ float tanh_(float x){ return 2.f*__builtin_amdgcn_rcpf(1.f + __expf(-2.f*x)) - 1.f; }

__device__ __forceinline__ void stage16(const u16* g, u16* l){
  __builtin_amdgcn_global_load_lds(
      (const __attribute__((address_space(1))) unsigned int*)g,
      (__attribute__((address_space(3))) unsigned int*)l, 16, 0, 0);
}

// ---------------------------------------------------------------- prep ----
// Stream layout (50 phases x 24 frags x 1024 B per step):
//   c*4+0 : gi  [gi_r kf0..7][gi_z kf0..7][gi_n kf0..7]   (K=128)
//   c*4+1 : gh_r kf0..23   c*4+2 : gh_z   c*4+3 : gh_n     (K=384)
//   48,49 : Wd1 col-tile 0,1  kf0..23
// frag: u16 idx (lane&31 + 32*(lane>>5))*8 + j -> B[k][n], n=c*32+(lane&31),
// k = kf*16 + (lane>>5)*8 + j
__global__ void prep_kernel(const float* __restrict__ Wih, const float* __restrict__ Whh,
                            const float* __restrict__ Wd1, const float* __restrict__ Wd2,
                            const float* __restrict__ bih, const float* __restrict__ bhh,
                            const float* __restrict__ Ws,  const float* __restrict__ bs,
                            const float* __restrict__ Wp,  const float* __restrict__ bp,
                            u16* __restrict__ stream, u16* __restrict__ wd2p,
                            u16* __restrict__ wxp, float* __restrict__ gb)
{
  int i = blockIdx.x*blockDim.x + threadIdx.x;
  if (i < 442368){  // W_hh [1152][384]
    int row = i/384, k = i - row*384;
    int g = row/384, unit = row - g*384, c = unit>>5, lc = unit&31;
    int kf = k>>4, hl = (k>>3)&1, j = k&7;
    int phase = c*4 + 1 + g;
    stream[(size_t)phase*PHU + kf*512 + (lc+32*hl)*8 + j] = f2b(Whh[i]);
  }
  if (i < 147456){  // W_ih [1152][128]
    int row = i>>7, k = i&127;
    int g = row/384, unit = row - g*384, c = unit>>5, lc = unit&31;
    int kf = k>>4, hl = (k>>3)&1, j = k&7;
    int phase = c*4;
    stream[(size_t)phase*PHU + (g*8+kf)*512 + (lc+32*hl)*8 + j] = f2b(Wih[i]);
  }
  if (i < 24576){   // Wd1 [64][384]
    int row = i/384, k = i - row*384;
    int ct = row>>5, lc = row&31;
    int kf = k>>4, hl = (k>>3)&1, j = k&7;
    int phase = 48 + ct;
    stream[(size_t)phase*PHU + kf*512 + (lc+32*hl)*8 + j] = f2b(Wd1[i]);
  }
  if (i < 2048){    // Wd2 padded B-frags [4 kf][512] (n>=3 -> 0)
    int kf = i>>9, r = i&511;
    int n = (r>>3)&31, hl = r>>8, j = r&7;
    int k = kf*16 + hl*8 + j;
    wd2p[i] = f2b((n<3) ? Wd2[n*64 + k] : 0.f);
  }
  if (i < 2048){    // x-MLP B-frags [4 tiles][512]: K=16 (k=0..7 feat, 8..15 zero)
    int tl = i>>9, r = i&511;
    int n = (r>>3)&31, hl = r>>8, j = r&7;
    int k = hl*8 + j, u = tl*32 + n;
    float v = 0.f;
    if      (k <= 2) v = Ws[u*3 + k];
    else if (k == 3) v = bs[u];
    else if (k <= 6) v = Wp[u*3 + (k-4)];
    else if (k == 7) v = bp[u];
    wxp[i] = f2b(v);
  }
  if (i < 384){     // fused gate biases per hidden unit: {r, z, n_i, n_h}
    gb[i*4+0] = bih[i]       + bhh[i];
    gb[i*4+1] = bih[384+i]   + bhh[384+i];
    gb[i*4+2] = bih[768+i];
    gb[i*4+3] = bhh[768+i];
  }
}

// ---------------------------------------------------------------- main ----
__global__ __launch_bounds__(256, 1)
void gru_main(const float* __restrict__ ih, const float* __restrict__ plan,
              const float* __restrict__ gate, const float* __restrict__ istate,
              const u16* __restrict__ stream, const u16* __restrict__ wd2p,
              const u16* __restrict__ wxp, const float* __restrict__ gb,
              const float* __restrict__ bd1, const float* __restrict__ bd2,
              float* __restrict__ out)
{
  __shared__ __attribute__((aligned(16))) u16 wb[2][PHU];   //  49152 B
  __shared__ __attribute__((aligned(16))) u16 hn[4][32*HS]; // 100352 B (wave-private h)
  __shared__ float sst[4][32][4];                           //   2048 B

  const int tid  = threadIdx.x;
  const int wave = tid >> 6, lane = tid & 63;
  const int m    = lane & 31, hl = lane >> 5;
  const int R0   = blockIdx.x*128 + wave*32;   // wave's 32 batch rows
  u16* hw = hn[wave];

  const float gt    = gate[R0 + m];
  const float bd1v0 = bd1[m], bd1v1 = bd1[32+m];
  const float bd2v  = (m<3) ? bd2[m] : 0.f;

  if (lane < 32){
    const float* sp = istate + (size_t)(R0+lane)*3;
    sst[wave][lane][0]=sp[0]; sst[wave][lane][1]=sp[1];
    sst[wave][lane][2]=sp[2]; sst[wave][lane][3]=0.f;
  }

  // initial hidden -> A-frags AND the persistent LDS h-buffer
  u16x8 hold[24];
#pragma unroll
  for (int kf=0; kf<24; ++kf){
    const float* p = ih + (size_t)(R0+m)*384 + kf*16 + hl*8;
    float4 a = *(const float4*)p;
    float4 b = *(const float4*)(p+4);
    u16x8 v;
    v[0]=f2b(a.x); v[1]=f2b(a.y); v[2]=f2b(a.z); v[3]=f2b(a.w);
    v[4]=f2b(b.x); v[5]=f2b(b.y); v[6]=f2b(b.z); v[7]=f2b(b.w);
    hold[kf]=v;
    *(u16x8*)&hw[m*HS + kf*16 + hl*8] = v;
  }

  const u16* srcb = stream + wave*3072 + lane*8;  // this wave's quarter + lane slot
  auto stage = [&](int ph, int bsel){
    const u16* s = srcb + (size_t)ph*PHU;
    u16* d = &wb[bsel][wave*3072];
#pragma unroll
    for (int ii=0; ii<6; ++ii) stage16(s + ii*512, d + ii*512);
  };

  stage(0, 0);
  vm_fence(); __syncthreads();
  int buf = 0, gp = 0;

#pragma unroll 1
  for (int t=0; t<TT; ++t){
    // ---- x = (state@Ws^T+bs) + gate*(plan@Wp^T+bp) via one padded-K MFMA per tile
    u16x8 a8;
    {
      float4 sv = *(const float4*)&sst[wave][m][0];
      const float* pp = plan + (size_t)(R0+m)*(TT*3) + t*3;
      float f0=sv.x, f1=sv.y, f2=sv.z, f3=1.f;
      float f4=gt*pp[0], f5=gt*pp[1], f6=gt*pp[2], f7=gt;
      if (hl){ a8[0]=0;a8[1]=0;a8[2]=0;a8[3]=0;a8[4]=0;a8[5]=0;a8[6]=0;a8[7]=0; }
      else { a8[0]=f2b(f0);a8[1]=f2b(f1);a8[2]=f2b(f2);a8[3]=f2b(f3);
             a8[4]=f2b(f4);a8[5]=f2b(f5);a8[6]=f2b(f6);a8[7]=f2b(f7); }
    }
    u16x8 xf[8];
#pragma unroll
    for (int tl=0; tl<4; ++tl){
      f32x16 ax;
#pragma unroll
      for (int r=0;r<16;++r) ax[r]=0.f;
      ax = mfma32(a8, *(const u16x8*)(wxp + tl*512 + lane*8), ax);
      // C-layout -> hn chunk-0 slice (scratch) -> A-frags
#pragma unroll
      for (int r=0;r<16;++r){
        int row = (r&3) + ((r>>2)<<3) + 4*hl;
        hw[row*HS + m] = f2b(ax[r]);
      }
      lds_fence();
      xf[2*tl]   = *(const u16x8*)&hw[m*HS + hl*8];
      xf[2*tl+1] = *(const u16x8*)&hw[m*HS + 16 + hl*8];
      lds_fence();
    }
    // restore chunk-0 slice of old h from hold (CONSTANT indices)
    *(u16x8*)&hw[m*HS + hl*8]      = hold[0];
    *(u16x8*)&hw[m*HS + 16 + hl*8] = hold[1];
    lds_fence();

#pragma unroll 1
    for (int c=0; c<12; ++c){
      f32x16 aR, aZ, aNI, aNH;
      {
        const float4 b4 = *(const float4*)(gb + (size_t)(c*32+m)*4);
#pragma unroll
        for (int r=0;r<16;++r){ aR[r]=b4.x; aZ[r]=b4.y; aNI[r]=b4.z; aNH[r]=b4.w; }
      }
      { // phase c*4: gi (r,z,n from x)
        int np = gp+1; stage(np, buf^1);
        const u16* W = wb[buf];
#pragma unroll
        for (int kf=0; kf<8; ++kf){
          u16x8 bR = *(const u16x8*)(W + (kf    )*512 + lane*8);
          u16x8 bZ = *(const u16x8*)(W + (8+kf  )*512 + lane*8);
          u16x8 bN = *(const u16x8*)(W + (16+kf )*512 + lane*8);
          aR  = mfma32(xf[kf], bR, aR);
          aZ  = mfma32(xf[kf], bZ, aZ);
          aNI = mfma32(xf[kf], bN, aNI);
        }
        vm_fence(); __syncthreads(); buf^=1; gp=np;
      }
      { // phase c*4+1: gh_r
        int np = gp+1; stage(np, buf^1);
        const u16* W = wb[buf];
#pragma unroll
        for (int kf=0; kf<24; ++kf)
          aR = mfma32(hold[kf], *(const u16x8*)(W + kf*512 + lane*8), aR);
        vm_fence(); __syncthreads(); buf^=1; gp=np;
      }
      { // phase c*4+2: gh_z
        int np = gp+1; stage(np, buf^1);
        const u16* W = wb[buf];
#pragma unroll
        for (int kf=0; kf<24; ++kf)
          aZ = mfma32(hold[kf], *(const u16x8*)(W + kf*512 + lane*8), aZ);
        vm_fence(); __syncthreads(); buf^=1; gp=np;
      }
      { // phase c*4+3: gh_n + GRU elementwise, blended in place in hn slice
        // (hn already holds old h for this chunk -- no register stores needed)
        int np = gp+1; stage(np, buf^1);
        const u16* W = wb[buf];
#pragma unroll
        for (int kf=0; kf<24; ++kf)
          aNH = mfma32(hold[kf], *(const u16x8*)(W + kf*512 + lane*8), aNH);
#pragma unroll
        for (int r=0;r<16;++r){
          int row = (r&3) + ((r>>2)<<3) + 4*hl;
          float rr = sigf(aR[r]);
          float zz = sigf(aZ[r]);
          float nn = tanh_(aNI[r] + rr*aNH[r]);
          int off = row*HS + c*32 + m;
          float ho = b2f(hw[off]);             // old h
          hw[off] = f2b((1.f-zz)*nn + zz*ho);  // new h, in place
        }
        vm_fence(); __syncthreads(); buf^=1; gp=np;
      }
    } // chunks

    // ---- reload hold[] from hn (full new h for this wave's 32 rows)
    lds_fence();
#pragma unroll
    for (int kf=0; kf<24; ++kf)
      hold[kf] = *(const u16x8*)&hw[m*HS + kf*16 + hl*8];

    // ---- decode: d1 = elu(h@Wd1^T + bd1) [2 tiles], then d2 via padded-N MFMA
    f32x16 a0, a1;
#pragma unroll
    for (int r=0;r<16;++r){ a0[r]=bd1v0; a1[r]=bd1v1; }
    { // phase 48: Wd1 tile 0
      int np = gp+1; stage(np, buf^1);
      const u16* W = wb[buf];
#pragma unroll
      for (int kf=0; kf<24; ++kf)
        a0 = mfma32(hold[kf], *(const u16x8*)(W + kf*512 + lane*8), a0);
      vm_fence(); __syncthreads(); buf^=1; gp=np;
    }
    { // phase 49: Wd1 tile 1 (+ epilogue); next stage wraps to phase 0
      int np = (gp+1 == NPH) ? 0 : gp+1;
      stage(np, buf^1);
      const u16* W = wb[buf];
#pragma unroll
      for (int kf=0; kf<24; ++kf)
        a1 = mfma32(hold[kf], *(const u16x8*)(W + kf*512 + lane*8), a1);

      // Wd2 frags (short live range, L1-hot)
      u16x8 wd2f0 = *(const u16x8*)(wd2p + 0*512 + lane*8);
      u16x8 wd2f1 = *(const u16x8*)(wd2p + 1*512 + lane*8);
      u16x8 wd2f2 = *(const u16x8*)(wd2p + 2*512 + lane*8);
      u16x8 wd2f3 = *(const u16x8*)(wd2p + 3*512 + lane*8);

      f32x16 ao;
#pragma unroll
      for (int r=0;r<16;++r) ao[r]=0.f;
      // pass 0: d1 units 0..31 (hn chunk-0 slice as scratch)
#pragma unroll
      for (int r=0;r<16;++r){
        int row = (r&3) + ((r>>2)<<3) + 4*hl;
        float e = a0[r]; e = e>0.f ? e : (__expf(e)-1.f);
        hw[row*HS + m] = f2b(e);
      }
      lds_fence();
      {
        u16x8 af0 = *(const u16x8*)&hw[m*HS + hl*8];
        u16x8 af1 = *(const u16x8*)&hw[m*HS + 16 + hl*8];
        ao = mfma32(af0, wd2f0, ao);
        ao = mfma32(af1, wd2f1, ao);
      }
      lds_fence();
      // pass 1: d1 units 32..63
#pragma unroll
      for (int r=0;r<16;++r){
        int row = (r&3) + ((r>>2)<<3) + 4*hl;
        float e = a1[r]; e = e>0.f ? e : (__expf(e)-1.f);
        hw[row*HS + m] = f2b(e);
      }
      lds_fence();
      {
        u16x8 af0 = *(const u16x8*)&hw[m*HS + hl*8];
        u16x8 af1 = *(const u16x8*)&hw[m*HS + 16 + hl*8];
        ao = mfma32(af0, wd2f2, ao);
        ao = mfma32(af1, wd2f3, ao);
      }
      lds_fence();
      // restore chunk-0 slice of NEW h from hold (CONSTANT indices)
      *(u16x8*)&hw[m*HS + hl*8]      = hold[0];
      *(u16x8*)&hw[m*HS + 16 + hl*8] = hold[1];

      // out + state update (C cols 0..2 valid)
#pragma unroll
      for (int r=0;r<16;++r){
        int row = (r&3) + ((r>>2)<<3) + 4*hl;
        if (m < 3){
          float ns = sst[wave][row][m] + ao[r] + bd2v;
          out[(size_t)(R0+row)*(TT*3) + t*3 + m] = ns;
          sst[wave][row][m] = ns;
        }
      }
      vm_fence(); __syncthreads(); buf^=1; gp=np;
    }
  } // t
}

// -------------------------------------------------------------- launch ----
extern "C" void kernel_launch(void* const* d_in, const int* in_sizes, int n_in,
                              void* d_out, int out_size, void* d_ws, size_t ws_size,
                              hipStream_t stream)
{
  (void)in_sizes; (void)n_in; (void)out_size; (void)ws_size;
  const float* ih     = (const float*)d_in[0];
  const float* plan   = (const float*)d_in[1];
  const float* gatep  = (const float*)d_in[2];
  const float* istate = (const float*)d_in[3];
  const float* Wp     = (const float*)d_in[4];
  const float* bp     = (const float*)d_in[5];
  const float* Ws     = (const float*)d_in[6];
  const float* bs     = (const float*)d_in[7];
  const float* Wih    = (const float*)d_in[8];
  const float* bih    = (const float*)d_in[9];
  const float* Whh    = (const float*)d_in[10];
  const float* bhh    = (const float*)d_in[11];
  const float* Wd1    = (const float*)d_in[12];
  const float* bd1    = (const float*)d_in[13];
  const float* Wd2    = (const float*)d_in[14];
  const float* bd2    = (const float*)d_in[15];

  // workspace layout (~1.25 MB)
  u16*   wstream = (u16*)d_ws;                         // 614400 u16 = 1228800 B
  u16*   wd2p    = (u16*)((char*)d_ws + 1228800);      //   2048 u16 =    4096 B
  u16*   wxp     = (u16*)((char*)d_ws + 1232896);      //   2048 u16 =    4096 B
  float* gb      = (float*)((char*)d_ws + 1236992);    //   1536 f32 =    6144 B

  prep_kernel<<<1728, 256, 0, stream>>>(Wih, Whh, Wd1, Wd2, bih, bhh, Ws, bs, Wp, bp,
                                        wstream, wd2p, wxp, gb);
  gru_main<<<256, 256, 0, stream>>>(ih, plan, gatep, istate,
                                    wstream, wd2p, wxp, gb, bd1, bd2, (float*)d_out);
}